// Round 8
// baseline (222.851 us; speedup 1.0000x reference)
//
#include <hip/hip_runtime.h>

// ---- types ----
typedef __attribute__((ext_vector_type(8))) short  bf16x8;  // 8 bf16 = 4 VGPR
typedef __attribute__((ext_vector_type(4))) float  f32x4;

static __device__ __forceinline__ unsigned short f2bf(float f) {
    unsigned u = __float_as_uint(f);
    u += 0x7fffu + ((u >> 16) & 1u);      // RNE (inputs are finite)
    return (unsigned short)(u >> 16);
}

// ---------------------------------------------------------------------------
// Prep: At[bn][n][k] = bf16(A[bn][k][n]); 32*128*128 bf16 = 1 MB into d_ws.
// ---------------------------------------------------------------------------
__global__ __launch_bounds__(256) void prep_at_kernel(
        const float* __restrict__ A, unsigned short* __restrict__ At)
{
    int g   = blockIdx.x * 256 + threadIdx.x;   // 65536 total
    int bn  = g >> 11;
    int rem = g & 2047;
    int kc  = rem >> 7;                         // k octet
    int n   = rem & 127;

    const float* src = A + bn * 16384 + kc * 8 * 128 + n;
    unsigned h[4];
    #pragma unroll
    for (int j = 0; j < 4; ++j) {
        unsigned short lo = f2bf(src[(2 * j    ) * 128]);
        unsigned short hi = f2bf(src[(2 * j + 1) * 128]);
        h[j] = (unsigned)lo | ((unsigned)hi << 16);
    }
    uint4 pk = make_uint4(h[0], h[1], h[2], h[3]);
    *(uint4*)(At + bn * 16384 + n * 128 + kc * 8) = pk;
}

// ---------------------------------------------------------------------------
// Main: wave-decoupled streaming, ZERO in-loop barriers (R5 concept, made
// scratch-safe: plain local float4 arrays, compile-time indices via unrolled
// macros, no lambdas -> stay in VGPRs).
// Grid 1024 = 32 bn x 32 row-groups (512 rows each); block = 256 thr =
// 4 waves. Prologue: At block (32 KB bf16 [n][k], XOR-swizzled: 16B slot
// c ^= n&7 applied to SOURCE, LDS linear; reads use same XOR -> 32 B/bank
// = conflict-free floor) + this group's dx rows (4 KB) staged via
// global_load_lds; ONE __syncthreads; everything after is wave-private.
// Wave w: col-half (w&1), row-stream (w>>1); streams 16 tiles of 16 rows x
// K=128, double-buffered in registers (stA/stB, 8 float4 each). Compiler
// emits counted vmcnt automatically (stB issued before stA consumed).
// 16 independent waves/CU -> continuous HBM issue, no sync stalls.
// ---------------------------------------------------------------------------
__global__ __launch_bounds__(256, 4) void trans_main_kernel(
        const float* __restrict__ v,  const float* __restrict__ dx,
        const unsigned short* __restrict__ At, const float* __restrict__ Bm,
        const float* __restrict__ bsc, float* __restrict__ out)
{
    __shared__ unsigned short AtL[128 * 128];   // 32 KB, swizzled [n][k]
    __shared__ float2 dxl[512];                 // 4 KB, rows g*512..+512

    const int tid = threadIdx.x;
    const int wid = tid >> 6;
    const int l   = tid & 63;
    const int lr  = l & 15;
    const int lq  = l >> 4;
    const int half = wid & 1;                   // output col half (64 cols)
    const int rs   = wid >> 1;                  // row stream 0/1
    const int bn   = blockIdx.x >> 5;           // 0..31
    const int g    = blockIdx.x & 31;           // 0..31 (512-row group)

    // ---- stage At -> LDS (linear dest, inverse-swizzled source) ----
    {
        const unsigned short* src = At + bn * 16384;
        #pragma unroll
        for (int it = 0; it < 8; ++it) {
            int c16 = it * 256 + tid;           // 16B-chunk index (0..2047)
            int n   = c16 >> 4;
            int c   = c16 & 15;
            int sc  = c ^ (n & 7);              // involution
            __builtin_amdgcn_global_load_lds(
                (const __attribute__((address_space(1))) unsigned int*)
                    (src + n * 128 + sc * 8),
                (__attribute__((address_space(3))) unsigned int*)
                    ((char*)AtL + c16 * 16),
                16, 0, 0);
        }
    }
    // ---- stage dx rows for this group -> LDS (linear, 1 chunk/thread) ----
    __builtin_amdgcn_global_load_lds(
        (const __attribute__((address_space(1))) unsigned int*)
            (dx + g * 1024 + tid * 4),
        (__attribute__((address_space(3))) unsigned int*)
            ((char*)dxl + tid * 16),
        16, 0, 0);

    // ---- per-wave constants ----
    const float bias = *bsc;
    const int col0 = bn * 128 + half * 64;
    float2 bc[4];
    #pragma unroll
    for (int ni = 0; ni < 4; ++ni)
        bc[ni] = *(const float2*)(Bm + 2 * (col0 + ni * 16 + lr));

    const char* AtBh = (const char*)AtL + (half * 64 + lr) * 256;
    int xr[4];
    #pragma unroll
    for (int kq = 0; kq < 4; ++kq)
        xr[kq] = (((kq * 4 + lq) ^ (lr & 7)) << 4);

    const float* vb = v + (size_t)(g * 512 + rs * 16 + lr) * 4096
                        + bn * 128 + lq * 8;

    __syncthreads();                            // LDS ready; read-only after

#define VLOAD_TILE(ST, T)                                                 \
    do {                                                                  \
        const float* p_ = vb + (size_t)(T) * 32 * 4096;                   \
        _Pragma("unroll")                                                 \
        for (int kq = 0; kq < 4; ++kq) {                                  \
            ST[kq * 2]     = *(const float4*)(p_ + kq * 32);              \
            ST[kq * 2 + 1] = *(const float4*)(p_ + kq * 32 + 4);          \
        }                                                                 \
    } while (0)

#define COMPUTE_TILE(ST, T)                                               \
    do {                                                                  \
        f32x4 a0 = {0.f,0.f,0.f,0.f}, a1 = {0.f,0.f,0.f,0.f};             \
        f32x4 a2 = {0.f,0.f,0.f,0.f}, a3 = {0.f,0.f,0.f,0.f};             \
        _Pragma("unroll")                                                 \
        for (int kq = 0; kq < 4; ++kq) {                                  \
            float4 f0 = ST[kq * 2], f1 = ST[kq * 2 + 1];                  \
            union { bf16x8 vv; unsigned short s[8]; } u;                  \
            u.s[0] = f2bf(f0.x); u.s[1] = f2bf(f0.y);                     \
            u.s[2] = f2bf(f0.z); u.s[3] = f2bf(f0.w);                     \
            u.s[4] = f2bf(f1.x); u.s[5] = f2bf(f1.y);                     \
            u.s[6] = f2bf(f1.z); u.s[7] = f2bf(f1.w);                     \
            bf16x8 q0 = *(const bf16x8*)(AtBh +         xr[kq]);          \
            bf16x8 q1 = *(const bf16x8*)(AtBh + 4096  + xr[kq]);          \
            bf16x8 q2 = *(const bf16x8*)(AtBh + 8192  + xr[kq]);          \
            bf16x8 q3 = *(const bf16x8*)(AtBh + 12288 + xr[kq]);          \
            a0 = __builtin_amdgcn_mfma_f32_16x16x32_bf16(u.vv, q0, a0, 0,0,0); \
            a1 = __builtin_amdgcn_mfma_f32_16x16x32_bf16(u.vv, q1, a1, 0,0,0); \
            a2 = __builtin_amdgcn_mfma_f32_16x16x32_bf16(u.vv, q2, a2, 0,0,0); \
            a3 = __builtin_amdgcn_mfma_f32_16x16x32_bf16(u.vv, q3, a3, 0,0,0); \
        }                                                                 \
        _Pragma("unroll")                                                 \
        for (int jj = 0; jj < 4; ++jj) {                                  \
            const int rloc = rs * 16 + (T) * 32 + lq * 4 + jj;            \
            const float2 d = dxl[rloc];                                   \
            float* orow = out + (size_t)(g * 512 + rloc) * 4096           \
                              + col0 + lr;                                \
            float o0 = a0[jj] + d.x * bc[0].x + d.y * bc[0].y + bias;     \
            float o1 = a1[jj] + d.x * bc[1].x + d.y * bc[1].y + bias;     \
            float o2 = a2[jj] + d.x * bc[2].x + d.y * bc[2].y + bias;     \
            float o3 = a3[jj] + d.x * bc[3].x + d.y * bc[3].y + bias;     \
            orow[0]  = fmaxf(o0, 0.f);                                    \
            orow[16] = fmaxf(o1, 0.f);                                    \
            orow[32] = fmaxf(o2, 0.f);                                    \
            orow[48] = fmaxf(o3, 0.f);                                    \
        }                                                                 \
    } while (0)

    // ---- wave-private 2x-unrolled stream over 16 tiles ----
    float4 stA[8], stB[8];
    VLOAD_TILE(stA, 0);
    for (int u = 0; u < 8; ++u) {
        const int t = u * 2;
        VLOAD_TILE(stB, t + 1);
        COMPUTE_TILE(stA, t);
        if (u < 7) VLOAD_TILE(stA, t + 2);
        COMPUTE_TILE(stB, t + 1);
    }
#undef VLOAD_TILE
#undef COMPUTE_TILE
}

// ---------------------------------------------------------------------------
extern "C" void kernel_launch(void* const* d_in, const int* in_sizes, int n_in,
                              void* d_out, int out_size, void* d_ws, size_t ws_size,
                              hipStream_t stream)
{
    const float* v  = (const float*)d_in[0];   // [16384, 4096]
    const float* dx = (const float*)d_in[1];   // [16384, 2]
    const float* A  = (const float*)d_in[2];   // [32, 128, 128]
    const float* Bm = (const float*)d_in[3];   // [4096, 2]
    const float* b  = (const float*)d_in[4];   // scalar

    unsigned short* At = (unsigned short*)d_ws; // 1 MB: [32][128 n][128 k] bf16

    prep_at_kernel<<<dim3(256), dim3(256), 0, stream>>>(A, At);
    trans_main_kernel<<<dim3(1024), dim3(256), 0, stream>>>(v, dx, At, Bm, b,
                                                            (float*)d_out);
}

// Round 9
// 140.180 us; speedup vs baseline: 1.5897x; 1.5897x over previous
//
#include <hip/hip_runtime.h>

// ---- types ----
typedef __attribute__((ext_vector_type(8))) short  bf16x8;  // 8 bf16 = 4 VGPR
typedef __attribute__((ext_vector_type(4))) float  f32x4;

static __device__ __forceinline__ unsigned short f2bf(float f) {
    unsigned u = __float_as_uint(f);
    u += 0x7fffu + ((u >> 16) & 1u);      // RNE (inputs are finite)
    return (unsigned short)(u >> 16);
}

// ---------------------------------------------------------------------------
// Prep: At[bn][n][k] = bf16(A[bn][k][n]); 32*128*128 bf16 = 1 MB into d_ws.
// ---------------------------------------------------------------------------
__global__ __launch_bounds__(256) void prep_at_kernel(
        const float* __restrict__ A, unsigned short* __restrict__ At)
{
    int g   = blockIdx.x * 256 + threadIdx.x;   // 65536 total
    int bn  = g >> 11;
    int rem = g & 2047;
    int kc  = rem >> 7;                         // k octet
    int n   = rem & 127;

    const float* src = A + bn * 16384 + kc * 8 * 128 + n;
    unsigned h[4];
    #pragma unroll
    for (int j = 0; j < 4; ++j) {
        unsigned short lo = f2bf(src[(2 * j    ) * 128]);
        unsigned short hi = f2bf(src[(2 * j + 1) * 128]);
        h[j] = (unsigned)lo | ((unsigned)hi << 16);
    }
    uint4 pk = make_uint4(h[0], h[1], h[2], h[3]);
    *(uint4*)(At + bn * 16384 + n * 128 + kc * 8) = pk;
}

// ---------------------------------------------------------------------------
// Main (R6 schedule, re-blocked for 4 barrier groups/CU):
// R6/R7 post-mortem: counted vmcnt alone bought 3% because with 512-thr
// blocks only 2 barrier groups/CU exist -- during each group's compute+
// epilogue phase the HBM pipe idles. This version: 256-thr blocks (4 waves),
// tile 16 rows x 128 cols (8 KB), 3 buffers + 4 KB dx = 28 KB LDS, grid
// 1024 = 32 bn x 32 row-groups -> 4 blocks/CU, independently staggered.
// Wave wn owns 16 rows x 32 cols (bq[4][2]=32 regs + acc[2]=8 -> natural
// VGPR ~85, NO launch_bounds cap -- R4/R8 lesson: caps cause spills).
// At block -> registers once; dx rows (512, 4 KB) -> LDS via global_load_lds
// in prologue (ds_read in body => lgkm domain, doesn't disturb vmcnt).
// v tile XOR-swizzle (row&7)<<4 on pre-swizzled source + swizzled LDS read.
// Counted waits (per-thread ops/iter = 2 stage + 8 stores, in-order):
//   iter 0: vmcnt(2)   iter 1: vmcnt(10)   iters 2..30: vmcnt(18)
//   iter 31 (no stage ahead): vmcnt(16)
// ---------------------------------------------------------------------------
__global__ __launch_bounds__(256) void trans_main_kernel(
        const float* __restrict__ v,  const float* __restrict__ dx,
        const unsigned short* __restrict__ At, const float* __restrict__ Bm,
        const float* __restrict__ bsc, float* __restrict__ out)
{
    __shared__ float  lds[3][16 * 128];         // 24 KB
    __shared__ float2 dxl[512];                 // 4 KB

    const int tid = threadIdx.x;
    const int wn  = tid >> 6;                   // wave 0..3 = col quarter
    const int l   = tid & 63;
    const int lr  = l & 15;
    const int lq  = l >> 4;
    const int bn  = blockIdx.x >> 5;            // 0..31 (slow -> At L2-hot)
    const int g   = blockIdx.x & 31;            // 0..31 (512-row group)

    // ---- At block -> registers, once. b-frag: B[k=lq*8+j][n=col] ----
    bf16x8 bq[4][2];
    const unsigned short* atb = At + bn * 16384 + (wn * 32 + lr) * 128 + lq * 8;
    #pragma unroll
    for (int kq = 0; kq < 4; ++kq)
        #pragma unroll
        for (int ni = 0; ni < 2; ++ni)
            bq[kq][ni] = *(const bf16x8*)(atb + ni * 16 * 128 + kq * 32);

    // ---- epilogue constants ----
    const float bias = *bsc;
    const int col0 = bn * 128 + wn * 32;
    float2 bc[2];
    #pragma unroll
    for (int ni = 0; ni < 2; ++ni)
        bc[ni] = *(const float2*)(Bm + 2 * (col0 + ni * 16 + lr));

    // ---- dx rows for this 512-row group -> LDS (1 chunk/thread) ----
    __builtin_amdgcn_global_load_lds(
        (const __attribute__((address_space(1))) unsigned int*)
            (dx + (size_t)g * 1024 + tid * 4),
        (__attribute__((address_space(3))) unsigned int*)
            ((char*)dxl + tid * 16),
        16, 0, 0);

    // ---- async stage of one 16x128 tile (pre-swizzled source) ----
    auto stage = [&](int buf, int k) {
        const float* src = v + (size_t)(g * 32 + k) * 16 * 4096 + bn * 128;
        #pragma unroll
        for (int it = 0; it < 2; ++it) {
            int c16  = it * 256 + tid;          // 16B-chunk index (0..511)
            int row  = c16 >> 5;                // 32 chunks per 512B row
            int off  = (c16 & 31) << 4;
            int soff = off ^ ((row & 7) << 4);  // inverse-swizzled source
            const float* gp = src + (size_t)row * 4096 + (soff >> 2);
            __builtin_amdgcn_global_load_lds(
                (const __attribute__((address_space(1))) unsigned int*)gp,
                (__attribute__((address_space(3))) unsigned int*)
                    &lds[buf][c16 * 4],
                16, 0, 0);
        }
    };

    // ---- compute + fused epilogue for tile k from buffer buf ----
    auto body = [&](int buf, int k) {
        f32x4 acc[2];
        acc[0] = (f32x4){0.f, 0.f, 0.f, 0.f};
        acc[1] = (f32x4){0.f, 0.f, 0.f, 0.f};

        const char* Lb = (const char*)&lds[buf][0];
        const int rb = lr * 512;                // lane reads row lr
        const int m  = (lr & 7) << 4;
        #pragma unroll
        for (int kq = 0; kq < 4; ++kq) {
            const int base = kq * 128 + lq * 32;
            float4 f0 = *(const float4*)(Lb + rb + ((base     ) ^ m));
            float4 f1 = *(const float4*)(Lb + rb + ((base + 16) ^ m));
            union { bf16x8 vv; unsigned short s[8]; } u;
            u.s[0] = f2bf(f0.x); u.s[1] = f2bf(f0.y);
            u.s[2] = f2bf(f0.z); u.s[3] = f2bf(f0.w);
            u.s[4] = f2bf(f1.x); u.s[5] = f2bf(f1.y);
            u.s[6] = f2bf(f1.z); u.s[7] = f2bf(f1.w);
            acc[0] = __builtin_amdgcn_mfma_f32_16x16x32_bf16(
                         u.vv, bq[kq][0], acc[0], 0, 0, 0);
            acc[1] = __builtin_amdgcn_mfma_f32_16x16x32_bf16(
                         u.vv, bq[kq][1], acc[1], 0, 0, 0);
        }

        #pragma unroll
        for (int jj = 0; jj < 4; ++jj) {
            const int rloc = k * 16 + lq * 4 + jj;      // row within group
            const float2 d = dxl[rloc];                 // LDS (lgkm domain)
            float* orow = out + (size_t)(g * 512 + rloc) * 4096 + col0 + lr;
            float v0 = acc[0][jj] + d.x * bc[0].x + d.y * bc[0].y + bias;
            float v1 = acc[1][jj] + d.x * bc[1].x + d.y * bc[1].y + bias;
            orow[0]  = fmaxf(v0, 0.0f);
            orow[16] = fmaxf(v1, 0.0f);
        }
    };

    __syncthreads();                            // dxl ready (drains all)

    // ---- pipeline: depth-2 prefetch, counted vmcnt, raw barriers ----
    stage(0, 0);
    stage(1, 1);

    // iter 0: keep S(1) in flight
    asm volatile("s_waitcnt vmcnt(2) lgkmcnt(0)" ::: "memory");
    __builtin_amdgcn_s_barrier();
    __builtin_amdgcn_sched_barrier(0);
    stage(2, 2);
    body(0, 0);

    // iter 1: newest 10 = st(0) 8 + stage(2) 2 -> S(1) retired
    asm volatile("s_waitcnt vmcnt(10) lgkmcnt(0)" ::: "memory");
    __builtin_amdgcn_s_barrier();
    __builtin_amdgcn_sched_barrier(0);
    stage(0, 3);
    body(1, 1);

    for (int k = 2; k < 31; ++k) {
        asm volatile("s_waitcnt vmcnt(18) lgkmcnt(0)" ::: "memory");
        __builtin_amdgcn_s_barrier();
        __builtin_amdgcn_sched_barrier(0);
        if (k + 2 < 32) stage((k + 2) % 3, k + 2);
        body(k % 3, k);
    }

    // iter 31 (no stage): newest 16 = st(30) 8 + st(29) 8 -> S(31) retired
    asm volatile("s_waitcnt vmcnt(16) lgkmcnt(0)" ::: "memory");
    __builtin_amdgcn_s_barrier();
    __builtin_amdgcn_sched_barrier(0);
    body(31 % 3, 31);
}

// ---------------------------------------------------------------------------
extern "C" void kernel_launch(void* const* d_in, const int* in_sizes, int n_in,
                              void* d_out, int out_size, void* d_ws, size_t ws_size,
                              hipStream_t stream)
{
    const float* v  = (const float*)d_in[0];   // [16384, 4096]
    const float* dx = (const float*)d_in[1];   // [16384, 2]
    const float* A  = (const float*)d_in[2];   // [32, 128, 128]
    const float* Bm = (const float*)d_in[3];   // [4096, 2]
    const float* b  = (const float*)d_in[4];   // scalar

    unsigned short* At = (unsigned short*)d_ws; // 1 MB: [32][128 n][128 k] bf16

    prep_at_kernel<<<dim3(256), dim3(256), 0, stream>>>(A, At);
    trans_main_kernel<<<dim3(1024), dim3(256), 0, stream>>>(v, dx, At, Bm, b,
                                                            (float*)d_out);
}

// Round 10
// 106.655 us; speedup vs baseline: 2.0895x; 1.3143x over previous
//
#include <hip/hip_runtime.h>

// ---- types ----
typedef __attribute__((ext_vector_type(8))) short  bf16x8;  // 8 bf16 = 4 VGPR
typedef __attribute__((ext_vector_type(4))) float  f32x4;

static __device__ __forceinline__ unsigned short f2bf(float f) {
    unsigned u = __float_as_uint(f);
    u += 0x7fffu + ((u >> 16) & 1u);      // RNE (inputs are finite)
    return (unsigned short)(u >> 16);
}

// ---------------------------------------------------------------------------
// Prep: At[bn][n][k] = bf16(A[bn][k][n]); 32*128*128 bf16 = 1 MB into d_ws.
// ---------------------------------------------------------------------------
__global__ __launch_bounds__(256) void prep_at_kernel(
        const float* __restrict__ A, unsigned short* __restrict__ At)
{
    int g   = blockIdx.x * 256 + threadIdx.x;   // 65536 total
    int bn  = g >> 11;
    int rem = g & 2047;
    int kc  = rem >> 7;                         // k octet
    int n   = rem & 127;

    const float* src = A + bn * 16384 + kc * 8 * 128 + n;
    unsigned h[4];
    #pragma unroll
    for (int j = 0; j < 4; ++j) {
        unsigned short lo = f2bf(src[(2 * j    ) * 128]);
        unsigned short hi = f2bf(src[(2 * j + 1) * 128]);
        h[j] = (unsigned)lo | ((unsigned)hi << 16);
    }
    uint4 pk = make_uint4(h[0], h[1], h[2], h[3]);
    *(uint4*)(At + bn * 16384 + n * 128 + kc * 8) = pk;
}

// ---------------------------------------------------------------------------
// Main = R6 skeleton (best: 104.8 us) + two mechanisms:
//  (1) depth-3 prefetch, FOUR 32x128 f32 LDS buffers (64 KB + 8 KB dx):
//      2-3 tiles stay in flight across every barrier (R6's depth-2 collapsed
//      to <=1 at the wait) -- flattens the HBM issue saw-tooth.
//  (2) non-temporal stores for out (write-once stream): stops the 256 MB
//      store stream from evicting v in L2/L3 (R1 showed L3 absorbs ~110 MB
//      of v otherwise).
// Grid 512 = 32 bn x 16; 512 thr = 8 waves; wave (wm,wn) = 16 rows x 32 cols.
// At block -> regs once (bq[4][2]); dx rows (1024, 8 KB) -> LDS prologue.
// XOR-swizzle (row&7)<<4 on pre-swizzled global source + swizzled LDS read.
// In-order vmcnt arithmetic (ops/iter = 2 stage + 8 stores):
//   iter0: 4   iter1: 12   iter2: 20   iters 3..29: 28   iter30: 26
//   iter31: 24  (stage of S(k+3) happens at iter k; last stage at k=28)
// ---------------------------------------------------------------------------
__global__ __launch_bounds__(512, 4) void trans_main_kernel(
        const float* __restrict__ v,  const float* __restrict__ dx,
        const unsigned short* __restrict__ At, const float* __restrict__ Bm,
        const float* __restrict__ bsc, float* __restrict__ out)
{
    __shared__ float  lds[4][32 * 128];         // 64 KB
    __shared__ float2 dxl[1024];                // 8 KB

    const int tid = threadIdx.x;
    const int wid = tid >> 6;
    const int l   = tid & 63;
    const int lr  = l & 15;
    const int lq  = l >> 4;
    const int wm  = wid >> 2;                   // 0..1 (16-row half)
    const int wn  = wid & 3;                    // 0..3 (32-col quarter)
    const int bn     = blockIdx.x >> 4;         // 0..31
    const int mtbase = blockIdx.x & 15;         // 0..15

    // ---- At block -> registers, once. b-frag: B[k=lq*8+j][n=col] ----
    bf16x8 bq[4][2];
    const unsigned short* atb = At + bn * 16384 + (wn * 32 + lr) * 128 + lq * 8;
    #pragma unroll
    for (int kq = 0; kq < 4; ++kq)
        #pragma unroll
        for (int ni = 0; ni < 2; ++ni)
            bq[kq][ni] = *(const bf16x8*)(atb + ni * 16 * 128 + kq * 32);

    // ---- epilogue constants ----
    const float bias = *bsc;
    const int col0 = bn * 128 + wn * 32;
    float2 bc[2];
    #pragma unroll
    for (int ni = 0; ni < 2; ++ni)
        bc[ni] = *(const float2*)(Bm + 2 * (col0 + ni * 16 + lr));

    // ---- dx rows for this block's 32 tiles -> LDS (prologue only) ----
    #pragma unroll
    for (int it = 0; it < 2; ++it) {
        int idx  = it * 512 + tid;              // 0..1023
        int kk   = idx >> 5;                    // tile 0..31
        int r    = idx & 31;                    // row in tile
        int grow = (kk * 16 + mtbase) * 32 + r;
        dxl[idx] = *(const float2*)(dx + 2 * grow);
    }

    // ---- async stage of one 32x128 tile (pre-swizzled source) ----
    auto stage = [&](int buf, int k) {
        const float* src = v + (size_t)(k * 16 + mtbase) * 32 * 4096 + bn * 128;
        #pragma unroll
        for (int it = 0; it < 2; ++it) {
            int c16  = it * 512 + tid;          // 16B-chunk index (0..1023)
            int row  = c16 >> 5;                // 32 chunks per 512B row
            int off  = (c16 & 31) << 4;
            int soff = off ^ ((row & 7) << 4);  // inverse-swizzled source
            const float* g = src + (size_t)row * 4096 + (soff >> 2);
            __builtin_amdgcn_global_load_lds(
                (const __attribute__((address_space(1))) unsigned int*)g,
                (__attribute__((address_space(3))) unsigned int*)
                    &lds[buf][c16 * 4],
                16, 0, 0);
        }
    };

    // ---- compute + fused epilogue for tile k from buffer buf ----
    auto body = [&](int buf, int k) {
        const int mt = k * 16 + mtbase;
        f32x4 acc[2];
        acc[0] = (f32x4){0.f, 0.f, 0.f, 0.f};
        acc[1] = (f32x4){0.f, 0.f, 0.f, 0.f};

        const char* Lb = (const char*)&lds[buf][0];
        const int row = wm * 16 + lr;
        const int rb  = row * 512;
        const int m   = (row & 7) << 4;
        #pragma unroll
        for (int kq = 0; kq < 4; ++kq) {
            const int base = kq * 128 + lq * 32;
            float4 f0 = *(const float4*)(Lb + rb + ((base     ) ^ m));
            float4 f1 = *(const float4*)(Lb + rb + ((base + 16) ^ m));
            union { bf16x8 vv; unsigned short s[8]; } u;
            u.s[0] = f2bf(f0.x); u.s[1] = f2bf(f0.y);
            u.s[2] = f2bf(f0.z); u.s[3] = f2bf(f0.w);
            u.s[4] = f2bf(f1.x); u.s[5] = f2bf(f1.y);
            u.s[6] = f2bf(f1.z); u.s[7] = f2bf(f1.w);
            acc[0] = __builtin_amdgcn_mfma_f32_16x16x32_bf16(
                         u.vv, bq[kq][0], acc[0], 0, 0, 0);
            acc[1] = __builtin_amdgcn_mfma_f32_16x16x32_bf16(
                         u.vv, bq[kq][1], acc[1], 0, 0, 0);
        }

        #pragma unroll
        for (int jj = 0; jj < 4; ++jj) {
            const int rl   = k * 32 + wm * 16 + lq * 4 + jj;  // dxl index
            const int rowg = mt * 32 + wm * 16 + lq * 4 + jj;
            const float2 d = dxl[rl];                          // LDS read
            float* orow = out + (size_t)rowg * 4096 + col0 + lr;
            float v0 = acc[0][jj] + d.x * bc[0].x + d.y * bc[0].y + bias;
            float v1 = acc[1][jj] + d.x * bc[1].x + d.y * bc[1].y + bias;
            __builtin_nontemporal_store(fmaxf(v0, 0.0f), orow);
            __builtin_nontemporal_store(fmaxf(v1, 0.0f), orow + 16);
        }
    };

    __syncthreads();                            // dxl ready (drains all)

    // ---- pipeline: depth-3 prefetch, counted vmcnt, raw barriers ----
    stage(0, 0);
    stage(1, 1);
    stage(2, 2);

    // iter 0: keep S(1),S(2) in flight
    asm volatile("s_waitcnt vmcnt(4) lgkmcnt(0)" ::: "memory");
    __builtin_amdgcn_s_barrier();
    __builtin_amdgcn_sched_barrier(0);
    stage(3, 3);
    body(0, 0);

    // iter 1: newer than S(1): S(2) 2 + S(3) 2 + st(0) 8 = 12
    asm volatile("s_waitcnt vmcnt(12) lgkmcnt(0)" ::: "memory");
    __builtin_amdgcn_s_barrier();
    __builtin_amdgcn_sched_barrier(0);
    stage(0, 4);
    body(1, 1);

    // iter 2: newer than S(2): S3 2 + st0 8 + S4 2 + st1 8 = 20
    asm volatile("s_waitcnt vmcnt(20) lgkmcnt(0)" ::: "memory");
    __builtin_amdgcn_s_barrier();
    __builtin_amdgcn_sched_barrier(0);
    stage(1, 5);
    body(2, 2);

    for (int k = 3; k < 30; ++k) {
        // newer than S(k): st(k-3) 8 + S(k+1) 2 + st(k-2) 8 + S(k+2) 2
        //                + st(k-1) 8 = 28
        asm volatile("s_waitcnt vmcnt(28) lgkmcnt(0)" ::: "memory");
        __builtin_amdgcn_s_barrier();
        __builtin_amdgcn_sched_barrier(0);
        if (k + 3 < 32) stage((k + 3) & 3, k + 3);
        body(k & 3, k);
    }

    // iter 30: newer than S(30): st(27) 8 + S(31) 2 + st(28) 8 + st(29) 8 = 26
    asm volatile("s_waitcnt vmcnt(26) lgkmcnt(0)" ::: "memory");
    __builtin_amdgcn_s_barrier();
    __builtin_amdgcn_sched_barrier(0);
    body(30 & 3, 30);

    // iter 31: newer than S(31): st(28) 8 + st(29) 8 + st(30) 8 = 24
    asm volatile("s_waitcnt vmcnt(24) lgkmcnt(0)" ::: "memory");
    __builtin_amdgcn_s_barrier();
    __builtin_amdgcn_sched_barrier(0);
    body(31 & 3, 31);
}

// ---------------------------------------------------------------------------
extern "C" void kernel_launch(void* const* d_in, const int* in_sizes, int n_in,
                              void* d_out, int out_size, void* d_ws, size_t ws_size,
                              hipStream_t stream)
{
    const float* v  = (const float*)d_in[0];   // [16384, 4096]
    const float* dx = (const float*)d_in[1];   // [16384, 2]
    const float* A  = (const float*)d_in[2];   // [32, 128, 128]
    const float* Bm = (const float*)d_in[3];   // [4096, 2]
    const float* b  = (const float*)d_in[4];   // scalar

    unsigned short* At = (unsigned short*)d_ws; // 1 MB: [32][128 n][128 k] bf16

    prep_at_kernel<<<dim3(256), dim3(256), 0, stream>>>(A, At);
    trans_main_kernel<<<dim3(512), dim3(512), 0, stream>>>(v, dx, At, Bm, b,
                                                           (float*)d_out);
}